// Round 7
// baseline (1001.524 us; speedup 1.0000x reference)
//
#include <hip/hip_runtime.h>
#include <hip/hip_bf16.h>

#define B_DIM 8
#define S_DIM 1024
#define D_DIM 1024
#define N_DIM 256
#define M_ROWS (B_DIM * S_DIM) /* 8192 */

typedef __attribute__((ext_vector_type(8))) short bf16x8;
typedef __attribute__((ext_vector_type(8))) unsigned short u16x8;
typedef __attribute__((ext_vector_type(4))) float f32x4;
typedef __attribute__((ext_vector_type(2))) float f32x2;

static __device__ __forceinline__ unsigned short f2bf(float f) {
  union { __hip_bfloat16 h; unsigned short s; } u;
  u.h = __float2bfloat16(f);
  return u.s;
}

static __device__ __forceinline__ float log1p_fast(float x) {
  return __logf(1.0f + x);
}

// Forced VOP3P packed fp32 (v_pk_*_f32). Non-volatile: pure ops, scheduler
// stays free to reorder/CSE.
static __device__ __forceinline__ f32x2 pk_mul(f32x2 a, f32x2 b) {
  f32x2 d;
  asm("v_pk_mul_f32 %0, %1, %2" : "=v"(d) : "v"(a), "v"(b));
  return d;
}
static __device__ __forceinline__ f32x2 pk_fma(f32x2 a, f32x2 b, f32x2 c) {
  f32x2 d;
  asm("v_pk_fma_f32 %0, %1, %2, %3" : "=v"(d) : "v"(a), "v"(b), "v"(c));
  return d;
}
static __device__ __forceinline__ f32x2 pk_add(f32x2 a, f32x2 b) {
  f32x2 d;
  asm("v_pk_add_f32 %0, %1, %2" : "=v"(d) : "v"(a), "v"(b));
  return d;
}

// Barrier that does NOT drain vmcnt: LDS visibility only.
#define LDS_BARRIER()                                         \
  do {                                                        \
    asm volatile("s_waitcnt lgkmcnt(0)" ::: "memory");        \
    __builtin_amdgcn_s_barrier();                             \
    asm volatile("" ::: "memory");                            \
  } while (0)

// ---------------------------------------------------------------------------
// GEMM1: KV[8192][512] = x[8192][1024] @ [Wk;Wv]([512][1024])^T   (bf16 MFMA)
// ---------------------------------------------------------------------------
__global__ __launch_bounds__(256) void gemm_kv(const float* __restrict__ x,
                                               const float* __restrict__ Wk,
                                               const float* __restrict__ Wv,
                                               float* __restrict__ KV) {
  __shared__ unsigned short lsA[128 * 40];
  __shared__ unsigned short lsB[128 * 40];
  const int tid = threadIdx.x;
  const int row0 = blockIdx.y * 128;
  const int col0 = blockIdx.x * 128;
  const float* Bsrc = (col0 < 256) ? (Wk + (size_t)col0 * 1024)
                                   : (Wv + (size_t)(col0 - 256) * 1024);
  const int sr = tid >> 1, sh = tid & 1;
  const float* ap = x + (size_t)(row0 + sr) * 1024 + sh * 16;
  const float* bp = Bsrc + (size_t)sr * 1024 + sh * 16;
  unsigned short* wa = &lsA[sr * 40 + sh * 16];
  unsigned short* wb = &lsB[sr * 40 + sh * 16];

  const int lane = tid & 63;
  const int w = tid >> 6, wr = w >> 1, wc = w & 1;
  const int fr = lane & 15, fk = lane >> 4;

  f32x4 acc[4][4];
#pragma unroll
  for (int m = 0; m < 4; ++m)
#pragma unroll
    for (int n = 0; n < 4; ++n) acc[m][n] = (f32x4){0.f, 0.f, 0.f, 0.f};

  for (int kt = 0; kt < 32; ++kt) {
    const float* a = ap + kt * 32;
    const float* b = bp + kt * 32;
    f32x4 A0 = *(const f32x4*)(a + 0), A1 = *(const f32x4*)(a + 4);
    f32x4 A2 = *(const f32x4*)(a + 8), A3 = *(const f32x4*)(a + 12);
    f32x4 B0 = *(const f32x4*)(b + 0), B1 = *(const f32x4*)(b + 4);
    f32x4 B2 = *(const f32x4*)(b + 8), B3 = *(const f32x4*)(b + 12);
    u16x8 pa0, pa1, pb0, pb1;
#pragma unroll
    for (int e = 0; e < 4; ++e) {
      pa0[e] = f2bf(A0[e]); pa0[e + 4] = f2bf(A1[e]);
      pa1[e] = f2bf(A2[e]); pa1[e + 4] = f2bf(A3[e]);
      pb0[e] = f2bf(B0[e]); pb0[e + 4] = f2bf(B1[e]);
      pb1[e] = f2bf(B2[e]); pb1[e + 4] = f2bf(B3[e]);
    }
    *(u16x8*)wa = pa0; *(u16x8*)(wa + 8) = pa1;
    *(u16x8*)wb = pb0; *(u16x8*)(wb + 8) = pb1;
    __syncthreads();
    bf16x8 af[4], bfr[4];
#pragma unroll
    for (int m = 0; m < 4; ++m)
      af[m] = *(const bf16x8*)(&lsA[(wr * 64 + m * 16 + fr) * 40 + fk * 8]);
#pragma unroll
    for (int n = 0; n < 4; ++n)
      bfr[n] = *(const bf16x8*)(&lsB[(wc * 64 + n * 16 + fr) * 40 + fk * 8]);
#pragma unroll
    for (int m = 0; m < 4; ++m)
#pragma unroll
      for (int n = 0; n < 4; ++n)
        acc[m][n] = __builtin_amdgcn_mfma_f32_16x16x32_bf16(af[m], bfr[n],
                                                            acc[m][n], 0, 0, 0);
    __syncthreads();
  }
#pragma unroll
  for (int m = 0; m < 4; ++m)
#pragma unroll
    for (int n = 0; n < 4; ++n) {
      const int col = col0 + wc * 64 + n * 16 + fr;
#pragma unroll
      for (int r = 0; r < 4; ++r) {
        const int row = row0 + wr * 64 + m * 16 + fk * 4 + r;
        KV[(size_t)row * 512 + col] = acc[m][n][r];
      }
    }
}

// ---------------------------------------------------------------------------
// gate[8192] = sigmoid(x @ Wg^T + bg)
// ---------------------------------------------------------------------------
__global__ __launch_bounds__(256) void gate_kernel(const float* __restrict__ x,
                                                   const float* __restrict__ Wg,
                                                   const float* __restrict__ bg,
                                                   float* __restrict__ gate) {
  const int row = blockIdx.x * 4 + (threadIdx.x >> 6);
  const int lane = threadIdx.x & 63;
  const f32x4* xr = (const f32x4*)(x + (size_t)row * 1024);
  const f32x4* wg = (const f32x4*)Wg;
  float s = 0.f;
#pragma unroll
  for (int c = 0; c < 4; ++c) {
    f32x4 a = xr[lane + 64 * c];
    f32x4 wv = wg[lane + 64 * c];
    s += a[0] * wv[0] + a[1] * wv[1] + a[2] * wv[2] + a[3] * wv[3];
  }
#pragma unroll
  for (int off = 32; off >= 1; off >>= 1) s += __shfl_xor(s, off, 64);
  if (lane == 0) gate[row] = 1.f / (1.f + __expf(-(s + bg[0])));
}

// ---------------------------------------------------------------------------
// WoP[d][i*16+k] = Wo[d][k*16+i]  (involution permute of columns)
// ---------------------------------------------------------------------------
__global__ __launch_bounds__(256) void wo_perm(const float* __restrict__ Wo,
                                               float* __restrict__ WoP) {
  const int d = blockIdx.x;
  const int c = threadIdx.x;
  WoP[(size_t)d * 256 + c] = Wo[(size_t)d * 256 + ((c & 15) * 16 + (c >> 4))];
}

// ---------------------------------------------------------------------------
// Sequential scan: 1 block per batch, 512 threads, thread (i,k,h):
// h in {0,1} owns j-slice [h*8, h*8+8). All inner math forced to
// v_pk_*_f32 (VOP3P). Cross-half sums via __shfl_xor(.,1). 2 waves/SIMD.
// ---------------------------------------------------------------------------
__global__ __launch_bounds__(512) void scan_kernel(const float* __restrict__ KV,
                                                   const float* __restrict__ gate,
                                                   unsigned short* __restrict__ ysbf,
                                                   float* __restrict__ err_out) {
  const int b = blockIdx.x;
  const int tid = threadIdx.x;       // 0..511
  const int i = tid >> 5;            // 0..15
  const int k = (tid >> 1) & 15;     // 0..15
  const int h = tid & 1;             // 0..1
  const int j0 = h * 8;

  __shared__ __align__(16) float hidT[2][16 * 20 + 4];  // [a][b] = hidden[b][a]
  __shared__ __align__(16) float errS[256];
  __shared__ __align__(16) float red[2][8];             // row-pair err^2 partials

  f32x2 w1p[4], w2p[4], w2tp[4], eyep[4];
#pragma unroll
  for (int p = 0; p < 4; ++p)
#pragma unroll
    for (int e = 0; e < 2; ++e) {
      const float v = ((j0 + p * 2 + e) == k) ? 1.f : 0.f;
      w1p[p][e] = v; w2p[p][e] = v; w2tp[p][e] = v; eyep[p][e] = v;
    }
  float strength = 0.f, last_seen = 0.f, pend = 0.f;

  const float* Kb = KV + (size_t)b * S_DIM * 512;
  const float* Gb = gate + (size_t)b * S_DIM;
  unsigned short* Yb = ysbf + (size_t)b * S_DIM * 256;
  float* Eb = err_out + (size_t)b * S_DIM;

  // ping-pong prefetch buffers (depth 2)
  f32x4 kqA0, kqA1, kqB0, kqB1;
  float vtA, vtB, gA, gB;
  {
    kqA0 = *(const f32x4*)(Kb + i * 16 + j0);
    kqA1 = *(const f32x4*)(Kb + i * 16 + j0 + 4);
    vtA = Kb[256 + i * 16 + k]; gA = Gb[0];
    kqB0 = *(const f32x4*)(Kb + 512 + i * 16 + j0);
    kqB1 = *(const f32x4*)(Kb + 512 + i * 16 + j0 + 4);
    vtB = Kb[512 + 256 + i * 16 + k]; gB = Gb[1];
  }

  auto step = [&](int s, f32x4& kq0, f32x4& kq1, float& vt, float& gv) {
    const int pb = s & 1;
    const float t = (float)(s + 1);
    const f32x2 kv2[4] = {{kq0[0], kq0[1]}, {kq0[2], kq0[3]},
                          {kq1[0], kq1[1]}, {kq1[2], kq1[3]}};

    // hidden[i][k] = sum_j kt[i][j] * w1[i][j][k]  (pk dot + DPP combine)
    f32x2 hacc = pk_mul(kv2[0], w1p[0]);
    hacc = pk_fma(kv2[1], w1p[1], hacc);
    hacc = pk_fma(kv2[2], w1p[2], hacc);
    hacc = pk_fma(kv2[3], w1p[3], hacc);
    const float hpart = hacc[0] + hacc[1];
    const float hidden = hpart + __shfl_xor(hpart, 1, 64);
    if (h == 0) hidT[pb][k * 20 + i] = hidden;

    // pre-barrier scalar work
    const float delta = t - last_seen;
    const float m_pre = fmaxf(log1p_fast(delta * 0.1f), 1.f);
    f32x2 aacc = pk_mul(kv2[0], kv2[0]);
    aacc = pk_fma(kv2[1], kv2[1], aacc);
    aacc = pk_fma(kv2[2], kv2[2], aacc);
    aacc = pk_fma(kv2[3], kv2[3], aacc);
    const float apart = aacc[0] + aacc[1];
    const float act2 = apart + __shfl_xor(apart, 1, 64);
    const float pend_new = log1p_fast(delta) * sqrtf(act2) * gv * 0.05f;

    LDS_BARRIER();

    // hj = hidden[j][i] for j in [j0, j0+8)
    const f32x4 hq0 = *(const f32x4*)&hidT[pb][i * 20 + j0];
    const f32x4 hq1 = *(const f32x4*)&hidT[pb][i * 20 + j0 + 4];
    const float hkk = hidT[pb][i * 20 + k];  // hidden[k][i]
    const f32x2 hv2[4] = {{hq0[0], hq0[1]}, {hq0[2], hq0[3]},
                          {hq1[0], hq1[1]}, {hq1[2], hq1[3]}};

    // strength update with step s-1's err_norm (8 row-pair partials)
    if (s > 0) {
      const f32x4* rp = (const f32x4*)&red[1 - pb][0];
      const f32x4 rs = rp[0] + rp[1];
      const float en = sqrtf((rs[0] + rs[1]) + (rs[2] + rs[3]));
      strength += pend * __builtin_amdgcn_rcpf(1.f + en);
      if (tid == 0) Eb[s - 1] = en;
    }
    const float df = 0.05f * m_pre * __builtin_amdgcn_rcpf(m_pre + strength);
    const float am = 1.f - df;

    // vt_pred[i][k] = sum_j hidden[j][i] * w2[i][j][k]
    f32x2 vacc = pk_mul(hv2[0], w2p[0]);
    vacc = pk_fma(hv2[1], w2p[1], vacc);
    vacc = pk_fma(hv2[2], w2p[2], vacc);
    vacc = pk_fma(hv2[3], w2p[3], vacc);
    const float vpart = vacc[0] + vacc[1];
    const float vt_pred = vpart + __shfl_xor(vpart, 1, 64);
    if (h == 0) Yb[(size_t)s * 256 + i * 16 + k] = f2bf(vt_pred);

    const float err = vt_pred - vt;

    // intra-wave err row exchange
    if (h == 0) errS[i * 16 + k] = err;
    asm volatile("s_waitcnt lgkmcnt(0)" ::: "memory");
    const f32x4 eq0 = *(const f32x4*)&errS[i * 16 + j0];
    const f32x4 eq1 = *(const f32x4*)&errS[i * 16 + j0 + 4];
    const f32x2 ev2[4] = {{eq0[0], eq0[1]}, {eq0[2], eq0[3]},
                          {eq1[0], eq1[1]}, {eq1[2], eq1[3]}};

    // per-row err^2 -> row-pair partial (xor32 crosses the two rows in wave)
    f32x2 eacc = pk_mul(ev2[0], ev2[0]);
    eacc = pk_fma(ev2[1], ev2[1], eacc);
    eacc = pk_fma(ev2[2], ev2[2], eacc);
    eacc = pk_fma(ev2[3], ev2[3], eacc);
    const float epart = eacc[0] + eacc[1];
    const float e2row = epart + __shfl_xor(epart, 1, 64);
    const float e2pair = e2row + __shfl_xor(e2row, 32, 64);
    if ((tid & 63) == 0) red[pb][tid >> 6] = e2pair;

    // grad_h[i][k] = sum_j err[i][j] * w2[i][k][j]
    f32x2 gacc = pk_mul(ev2[0], w2tp[0]);
    gacc = pk_fma(ev2[1], w2tp[1], gacc);
    gacc = pk_fma(ev2[2], w2tp[2], gacc);
    gacc = pk_fma(ev2[3], w2tp[3], gacc);
    const float gpart = gacc[0] + gacc[1];
    const float gh = gpart + __shfl_xor(gpart, 1, 64);

    const float slr = 0.1f * gv;
    const float nsg = -slr * gh;
    const float nse = -slr * err;
    const float nsh = -slr * hkk;
    const f32x2 am2 = {am, am};
    const f32x2 df2 = {df, df};
    const f32x2 nsg2 = {nsg, nsg};
    const f32x2 nse2 = {nse, nse};
    const f32x2 nsh2 = {nsh, nsh};
#pragma unroll
    for (int p = 0; p < 4; ++p) {
      const f32x2 dfp = pk_mul(eyep[p], df2);
      w1p[p] = pk_fma(pk_fma(nsg2, kv2[p], w1p[p]), am2, dfp);
      w2p[p] = pk_fma(pk_fma(nse2, hv2[p], w2p[p]), am2, dfp);
      w2tp[p] = pk_fma(pk_fma(nsh2, ev2[p], w2tp[p]), am2, dfp);
    }

    pend = pend_new;
    if (act2 > 0.01f) last_seen = t;

    // prefetch step s+2 (stray tail reads stay inside ws)
    {
      const float* base = Kb + (size_t)(s + 2) * 512;
      kq0 = *(const f32x4*)(base + i * 16 + j0);
      kq1 = *(const f32x4*)(base + i * 16 + j0 + 4);
      vt = base[256 + i * 16 + k];
      gv = Gb[s + 2];
    }
  };

  for (int s = 0; s < S_DIM; s += 2) {
    step(s, kqA0, kqA1, vtA, gA);
    step(s + 1, kqB0, kqB1, vtB, gB);
  }
  LDS_BARRIER();
  if (tid == 0) {
    const f32x4* rp = (const f32x4*)&red[1][0];  // s=1023 parity = 1
    const f32x4 rs = rp[0] + rp[1];
    Eb[S_DIM - 1] = sqrtf((rs[0] + rs[1]) + (rs[2] + rs[3]));
  }
}

// ---------------------------------------------------------------------------
// GEMM2: out[8192][1024] = ysP[8192][256](bf16) @ WoP([1024][256])^T + bo
// ---------------------------------------------------------------------------
__global__ __launch_bounds__(256) void gemm_out(const unsigned short* __restrict__ ysbf,
                                                const float* __restrict__ WoP,
                                                const float* __restrict__ bo,
                                                float* __restrict__ out) {
  __shared__ unsigned short lsA[128 * 40];
  __shared__ unsigned short lsB[128 * 40];
  const int tid = threadIdx.x;
  const int row0 = blockIdx.y * 128;
  const int col0 = blockIdx.x * 128;
  const int sr = tid >> 1, sh = tid & 1;
  const unsigned short* ap = ysbf + (size_t)(row0 + sr) * 256 + sh * 16;
  const float* bp = WoP + (size_t)(col0 + sr) * 256 + sh * 16;
  unsigned short* wa = &lsA[sr * 40 + sh * 16];
  unsigned short* wb = &lsB[sr * 40 + sh * 16];

  const int lane = tid & 63;
  const int w = tid >> 6, wr = w >> 1, wc = w & 1;
  const int fr = lane & 15, fk = lane >> 4;

  f32x4 acc[4][4];
#pragma unroll
  for (int m = 0; m < 4; ++m)
#pragma unroll
    for (int n = 0; n < 4; ++n) acc[m][n] = (f32x4){0.f, 0.f, 0.f, 0.f};

  for (int kt = 0; kt < 8; ++kt) {
    u16x8 pa0 = *(const u16x8*)(ap + kt * 32);
    u16x8 pa1 = *(const u16x8*)(ap + kt * 32 + 8);
    const float* bq = bp + kt * 32;
    f32x4 B0 = *(const f32x4*)(bq + 0), B1 = *(const f32x4*)(bq + 4);
    f32x4 B2 = *(const f32x4*)(bq + 8), B3 = *(const f32x4*)(bq + 12);
    u16x8 pb0, pb1;
#pragma unroll
    for (int e = 0; e < 4; ++e) {
      pb0[e] = f2bf(B0[e]); pb0[e + 4] = f2bf(B1[e]);
      pb1[e] = f2bf(B2[e]); pb1[e + 4] = f2bf(B3[e]);
    }
    *(u16x8*)wa = pa0; *(u16x8*)(wa + 8) = pa1;
    *(u16x8*)wb = pb0; *(u16x8*)(wb + 8) = pb1;
    __syncthreads();
    bf16x8 af[4], bfr[4];
#pragma unroll
    for (int m = 0; m < 4; ++m)
      af[m] = *(const bf16x8*)(&lsA[(wr * 64 + m * 16 + fr) * 40 + fk * 8]);
#pragma unroll
    for (int n = 0; n < 4; ++n)
      bfr[n] = *(const bf16x8*)(&lsB[(wc * 64 + n * 16 + fr) * 40 + fk * 8]);
#pragma unroll
    for (int m = 0; m < 4; ++m)
#pragma unroll
      for (int n = 0; n < 4; ++n)
        acc[m][n] = __builtin_amdgcn_mfma_f32_16x16x32_bf16(af[m], bfr[n],
                                                            acc[m][n], 0, 0, 0);
    __syncthreads();
  }
#pragma unroll
  for (int m = 0; m < 4; ++m)
#pragma unroll
    for (int n = 0; n < 4; ++n) {
      const int col = col0 + wc * 64 + n * 16 + fr;
      const float bias = bo[col];
#pragma unroll
      for (int r = 0; r < 4; ++r) {
        const int row = row0 + wr * 64 + m * 16 + fk * 4 + r;
        out[(size_t)row * 1024 + col] = acc[m][n][r] + bias;
      }
    }
}

// ---------------------------------------------------------------------------
extern "C" void kernel_launch(void* const* d_in, const int* in_sizes, int n_in,
                              void* d_out, int out_size, void* d_ws, size_t ws_size,
                              hipStream_t stream) {
  const float* x = (const float*)d_in[0];
  const float* Wk = (const float*)d_in[1];
  const float* Wv = (const float*)d_in[2];
  const float* Wg = (const float*)d_in[3];
  const float* bg = (const float*)d_in[4];
  const float* Wo = (const float*)d_in[5];
  const float* bo = (const float*)d_in[6];

  float* out = (float*)d_out;                        // [8192][1024]
  float* err_out = out + (size_t)M_ROWS * 1024;      // [8192]

  char* ws = (char*)d_ws;
  float* KV = (float*)ws;                                        // 16 MB
  float* gate = (float*)(ws + (size_t)M_ROWS * 512 * 4);         // 32 KB
  unsigned short* ysbf =
      (unsigned short*)(ws + (size_t)M_ROWS * 512 * 4 + 32768);  // 4 MB
  float* WoP = (float*)(ws + (size_t)M_ROWS * 512 * 4 + 32768 +
                        (size_t)M_ROWS * 256 * 2);               // 1 MB

  gemm_kv<<<dim3(4, 64), 256, 0, stream>>>(x, Wk, Wv, KV);
  gate_kernel<<<dim3(2048), 256, 0, stream>>>(x, Wg, bg, gate);
  wo_perm<<<dim3(1024), 256, 0, stream>>>(Wo, WoP);
  scan_kernel<<<dim3(8), 512, 0, stream>>>(KV, gate, ysbf, err_out);
  gemm_out<<<dim3(8, 64), 256, 0, stream>>>(ysbf, WoP, bo, out);
}

// Round 8
// 910.235 us; speedup vs baseline: 1.1003x; 1.1003x over previous
//
#include <hip/hip_runtime.h>
#include <hip/hip_bf16.h>

#define B_DIM 8
#define S_DIM 1024
#define D_DIM 1024
#define N_DIM 256
#define M_ROWS (B_DIM * S_DIM) /* 8192 */

typedef __attribute__((ext_vector_type(8))) short bf16x8;
typedef __attribute__((ext_vector_type(8))) unsigned short u16x8;
typedef __attribute__((ext_vector_type(4))) float f32x4;
typedef __attribute__((ext_vector_type(2))) float f32x2;

static __device__ __forceinline__ unsigned short f2bf(float f) {
  union { __hip_bfloat16 h; unsigned short s; } u;
  u.h = __float2bfloat16(f);
  return u.s;
}

static __device__ __forceinline__ float log1p_fast(float x) {
  return __logf(1.0f + x);
}

// Forced VOP3P packed fp32 (v_pk_*_f32).
static __device__ __forceinline__ f32x2 pk_mul(f32x2 a, f32x2 b) {
  f32x2 d;
  asm("v_pk_mul_f32 %0, %1, %2" : "=v"(d) : "v"(a), "v"(b));
  return d;
}
static __device__ __forceinline__ f32x2 pk_fma(f32x2 a, f32x2 b, f32x2 c) {
  f32x2 d;
  asm("v_pk_fma_f32 %0, %1, %2, %3" : "=v"(d) : "v"(a), "v"(b), "v"(c));
  return d;
}

// lane^1 exchange via DPP quad_perm [1,0,3,2] — pure VALU, no ds_bpermute.
static __device__ __forceinline__ float dpp_swap1(float x) {
  int r = __builtin_amdgcn_update_dpp(0, __builtin_bit_cast(int, x),
                                      0xB1, 0xF, 0xF, true);
  return __builtin_bit_cast(float, r);
}
// pairwise sum across lane^1
static __device__ __forceinline__ float pair_sum(float x) {
  return x + dpp_swap1(x);
}

// Barrier that does NOT drain vmcnt: LDS visibility only.
#define LDS_BARRIER()                                         \
  do {                                                        \
    asm volatile("s_waitcnt lgkmcnt(0)" ::: "memory");        \
    __builtin_amdgcn_s_barrier();                             \
    asm volatile("" ::: "memory");                            \
  } while (0)

// ---------------------------------------------------------------------------
// GEMM1: KV[8192][512] = x[8192][1024] @ [Wk;Wv]([512][1024])^T   (bf16 MFMA)
// ---------------------------------------------------------------------------
__global__ __launch_bounds__(256) void gemm_kv(const float* __restrict__ x,
                                               const float* __restrict__ Wk,
                                               const float* __restrict__ Wv,
                                               float* __restrict__ KV) {
  __shared__ unsigned short lsA[128 * 40];
  __shared__ unsigned short lsB[128 * 40];
  const int tid = threadIdx.x;
  const int row0 = blockIdx.y * 128;
  const int col0 = blockIdx.x * 128;
  const float* Bsrc = (col0 < 256) ? (Wk + (size_t)col0 * 1024)
                                   : (Wv + (size_t)(col0 - 256) * 1024);
  const int sr = tid >> 1, sh = tid & 1;
  const float* ap = x + (size_t)(row0 + sr) * 1024 + sh * 16;
  const float* bp = Bsrc + (size_t)sr * 1024 + sh * 16;
  unsigned short* wa = &lsA[sr * 40 + sh * 16];
  unsigned short* wb = &lsB[sr * 40 + sh * 16];

  const int lane = tid & 63;
  const int w = tid >> 6, wr = w >> 1, wc = w & 1;
  const int fr = lane & 15, fk = lane >> 4;

  f32x4 acc[4][4];
#pragma unroll
  for (int m = 0; m < 4; ++m)
#pragma unroll
    for (int n = 0; n < 4; ++n) acc[m][n] = (f32x4){0.f, 0.f, 0.f, 0.f};

  for (int kt = 0; kt < 32; ++kt) {
    const float* a = ap + kt * 32;
    const float* b = bp + kt * 32;
    f32x4 A0 = *(const f32x4*)(a + 0), A1 = *(const f32x4*)(a + 4);
    f32x4 A2 = *(const f32x4*)(a + 8), A3 = *(const f32x4*)(a + 12);
    f32x4 B0 = *(const f32x4*)(b + 0), B1 = *(const f32x4*)(b + 4);
    f32x4 B2 = *(const f32x4*)(b + 8), B3 = *(const f32x4*)(b + 12);
    u16x8 pa0, pa1, pb0, pb1;
#pragma unroll
    for (int e = 0; e < 4; ++e) {
      pa0[e] = f2bf(A0[e]); pa0[e + 4] = f2bf(A1[e]);
      pa1[e] = f2bf(A2[e]); pa1[e + 4] = f2bf(A3[e]);
      pb0[e] = f2bf(B0[e]); pb0[e + 4] = f2bf(B1[e]);
      pb1[e] = f2bf(B2[e]); pb1[e + 4] = f2bf(B3[e]);
    }
    *(u16x8*)wa = pa0; *(u16x8*)(wa + 8) = pa1;
    *(u16x8*)wb = pb0; *(u16x8*)(wb + 8) = pb1;
    __syncthreads();
    bf16x8 af[4], bfr[4];
#pragma unroll
    for (int m = 0; m < 4; ++m)
      af[m] = *(const bf16x8*)(&lsA[(wr * 64 + m * 16 + fr) * 40 + fk * 8]);
#pragma unroll
    for (int n = 0; n < 4; ++n)
      bfr[n] = *(const bf16x8*)(&lsB[(wc * 64 + n * 16 + fr) * 40 + fk * 8]);
#pragma unroll
    for (int m = 0; m < 4; ++m)
#pragma unroll
      for (int n = 0; n < 4; ++n)
        acc[m][n] = __builtin_amdgcn_mfma_f32_16x16x32_bf16(af[m], bfr[n],
                                                            acc[m][n], 0, 0, 0);
    __syncthreads();
  }
#pragma unroll
  for (int m = 0; m < 4; ++m)
#pragma unroll
    for (int n = 0; n < 4; ++n) {
      const int col = col0 + wc * 64 + n * 16 + fr;
#pragma unroll
      for (int r = 0; r < 4; ++r) {
        const int row = row0 + wr * 64 + m * 16 + fk * 4 + r;
        KV[(size_t)row * 512 + col] = acc[m][n][r];
      }
    }
}

// ---------------------------------------------------------------------------
// gate[8192] = sigmoid(x @ Wg^T + bg)
// ---------------------------------------------------------------------------
__global__ __launch_bounds__(256) void gate_kernel(const float* __restrict__ x,
                                                   const float* __restrict__ Wg,
                                                   const float* __restrict__ bg,
                                                   float* __restrict__ gate) {
  const int row = blockIdx.x * 4 + (threadIdx.x >> 6);
  const int lane = threadIdx.x & 63;
  const f32x4* xr = (const f32x4*)(x + (size_t)row * 1024);
  const f32x4* wg = (const f32x4*)Wg;
  float s = 0.f;
#pragma unroll
  for (int c = 0; c < 4; ++c) {
    f32x4 a = xr[lane + 64 * c];
    f32x4 wv = wg[lane + 64 * c];
    s += a[0] * wv[0] + a[1] * wv[1] + a[2] * wv[2] + a[3] * wv[3];
  }
#pragma unroll
  for (int off = 32; off >= 1; off >>= 1) s += __shfl_xor(s, off, 64);
  if (lane == 0) gate[row] = 1.f / (1.f + __expf(-(s + bg[0])));
}

// ---------------------------------------------------------------------------
// WoP[d][i*16+k] = Wo[d][k*16+i]  (involution permute of columns)
// ---------------------------------------------------------------------------
__global__ __launch_bounds__(256) void wo_perm(const float* __restrict__ Wo,
                                               float* __restrict__ WoP) {
  const int d = blockIdx.x;
  const int c = threadIdx.x;
  WoP[(size_t)d * 256 + c] = Wo[(size_t)d * 256 + ((c & 15) * 16 + (c >> 4))];
}

// ---------------------------------------------------------------------------
// Sequential scan: 1 block per batch, 512 threads, thread (i,k,h):
// h in {0,1} owns j-slice [h*8, h*8+8). Packed math (v_pk_*_f32);
// cross-half combines via DPP quad_perm (pure VALU — no ds_bpermute).
// ---------------------------------------------------------------------------
__global__ __launch_bounds__(512) void scan_kernel(const float* __restrict__ KV,
                                                   const float* __restrict__ gate,
                                                   unsigned short* __restrict__ ysbf,
                                                   float* __restrict__ err_out) {
  const int b = blockIdx.x;
  const int tid = threadIdx.x;       // 0..511
  const int i = tid >> 5;            // 0..15
  const int k = (tid >> 1) & 15;     // 0..15
  const int h = tid & 1;             // 0..1
  const int j0 = h * 8;

  __shared__ __align__(16) float hidT[2][16 * 20 + 4];  // [a][b] = hidden[b][a]
  __shared__ __align__(16) float errS[256];
  __shared__ __align__(16) float red[2][8];             // row-pair err^2 partials

  f32x2 w1p[4], w2p[4], w2tp[4], eyep[4];
#pragma unroll
  for (int p = 0; p < 4; ++p)
#pragma unroll
    for (int e = 0; e < 2; ++e) {
      const float v = ((j0 + p * 2 + e) == k) ? 1.f : 0.f;
      w1p[p][e] = v; w2p[p][e] = v; w2tp[p][e] = v; eyep[p][e] = v;
    }
  float strength = 0.f, last_seen = 0.f, pend = 0.f;

  const float* Kb = KV + (size_t)b * S_DIM * 512;
  const float* Gb = gate + (size_t)b * S_DIM;
  unsigned short* Yb = ysbf + (size_t)b * S_DIM * 256;
  float* Eb = err_out + (size_t)b * S_DIM;

  // ping-pong prefetch buffers (depth 2)
  f32x4 kqA0, kqA1, kqB0, kqB1;
  float vtA, vtB, gA, gB;
  {
    kqA0 = *(const f32x4*)(Kb + i * 16 + j0);
    kqA1 = *(const f32x4*)(Kb + i * 16 + j0 + 4);
    vtA = Kb[256 + i * 16 + k]; gA = Gb[0];
    kqB0 = *(const f32x4*)(Kb + 512 + i * 16 + j0);
    kqB1 = *(const f32x4*)(Kb + 512 + i * 16 + j0 + 4);
    vtB = Kb[512 + 256 + i * 16 + k]; gB = Gb[1];
  }

  auto step = [&](int s, f32x4& kq0, f32x4& kq1, float& vt, float& gv) {
    const int pb = s & 1;
    const float t = (float)(s + 1);
    const f32x2 kv2[4] = {{kq0[0], kq0[1]}, {kq0[2], kq0[3]},
                          {kq1[0], kq1[1]}, {kq1[2], kq1[3]}};

    // hidden[i][k] = sum_j kt[i][j] * w1[i][j][k]  (pk dot + DPP pair-sum)
    f32x2 hacc = pk_mul(kv2[0], w1p[0]);
    hacc = pk_fma(kv2[1], w1p[1], hacc);
    hacc = pk_fma(kv2[2], w1p[2], hacc);
    hacc = pk_fma(kv2[3], w1p[3], hacc);
    const float hidden = pair_sum(hacc[0] + hacc[1]);
    if (h == 0) hidT[pb][k * 20 + i] = hidden;

    // pre-barrier scalar work
    const float delta = t - last_seen;
    const float m_pre = fmaxf(log1p_fast(delta * 0.1f), 1.f);
    f32x2 aacc = pk_mul(kv2[0], kv2[0]);
    aacc = pk_fma(kv2[1], kv2[1], aacc);
    aacc = pk_fma(kv2[2], kv2[2], aacc);
    aacc = pk_fma(kv2[3], kv2[3], aacc);
    const float act2 = pair_sum(aacc[0] + aacc[1]);
    const float pend_new = log1p_fast(delta) * sqrtf(act2) * gv * 0.05f;

    LDS_BARRIER();

    // hj = hidden[j][i] for j in [j0, j0+8)
    const f32x4 hq0 = *(const f32x4*)&hidT[pb][i * 20 + j0];
    const f32x4 hq1 = *(const f32x4*)&hidT[pb][i * 20 + j0 + 4];
    const float hkk = hidT[pb][i * 20 + k];  // hidden[k][i]
    const f32x2 hv2[4] = {{hq0[0], hq0[1]}, {hq0[2], hq0[3]},
                          {hq1[0], hq1[1]}, {hq1[2], hq1[3]}};

    // strength update with step s-1's err_norm (8 row-pair partials)
    if (s > 0) {
      const f32x4* rp = (const f32x4*)&red[1 - pb][0];
      const f32x4 rs = rp[0] + rp[1];
      const float en = sqrtf((rs[0] + rs[1]) + (rs[2] + rs[3]));
      strength += pend * __builtin_amdgcn_rcpf(1.f + en);
      if (tid == 0) Eb[s - 1] = en;
    }
    const float df = 0.05f * m_pre * __builtin_amdgcn_rcpf(m_pre + strength);
    const float am = 1.f - df;

    // vt_pred[i][k] = sum_j hidden[j][i] * w2[i][j][k]
    f32x2 vacc = pk_mul(hv2[0], w2p[0]);
    vacc = pk_fma(hv2[1], w2p[1], vacc);
    vacc = pk_fma(hv2[2], w2p[2], vacc);
    vacc = pk_fma(hv2[3], w2p[3], vacc);
    const float vt_pred = pair_sum(vacc[0] + vacc[1]);
    if (h == 0) Yb[(size_t)s * 256 + i * 16 + k] = f2bf(vt_pred);

    const float err = vt_pred - vt;

    // intra-wave err row exchange
    if (h == 0) errS[i * 16 + k] = err;
    asm volatile("s_waitcnt lgkmcnt(0)" ::: "memory");
    const f32x4 eq0 = *(const f32x4*)&errS[i * 16 + j0];
    const f32x4 eq1 = *(const f32x4*)&errS[i * 16 + j0 + 4];
    const f32x2 ev2[4] = {{eq0[0], eq0[1]}, {eq0[2], eq0[3]},
                          {eq1[0], eq1[1]}, {eq1[2], eq1[3]}};

    // per-row err^2 -> row-pair partial (shfl32 crosses the two rows in wave)
    f32x2 eacc = pk_mul(ev2[0], ev2[0]);
    eacc = pk_fma(ev2[1], ev2[1], eacc);
    eacc = pk_fma(ev2[2], ev2[2], eacc);
    eacc = pk_fma(ev2[3], ev2[3], eacc);
    const float e2row = pair_sum(eacc[0] + eacc[1]);
    const float e2pair = e2row + __shfl_xor(e2row, 32, 64);
    if ((tid & 63) == 0) red[pb][tid >> 6] = e2pair;

    // grad_h[i][k] = sum_j err[i][j] * w2[i][k][j]
    f32x2 gacc = pk_mul(ev2[0], w2tp[0]);
    gacc = pk_fma(ev2[1], w2tp[1], gacc);
    gacc = pk_fma(ev2[2], w2tp[2], gacc);
    gacc = pk_fma(ev2[3], w2tp[3], gacc);
    const float gh = pair_sum(gacc[0] + gacc[1]);

    const float slr = 0.1f * gv;
    const float nsg = -slr * gh;
    const float nse = -slr * err;
    const float nsh = -slr * hkk;
    const f32x2 am2 = {am, am};
    const f32x2 df2 = {df, df};
    const f32x2 nsg2 = {nsg, nsg};
    const f32x2 nse2 = {nse, nse};
    const f32x2 nsh2 = {nsh, nsh};
#pragma unroll
    for (int p = 0; p < 4; ++p) {
      const f32x2 dfp = pk_mul(eyep[p], df2);
      w1p[p] = pk_fma(pk_fma(nsg2, kv2[p], w1p[p]), am2, dfp);
      w2p[p] = pk_fma(pk_fma(nse2, hv2[p], w2p[p]), am2, dfp);
      w2tp[p] = pk_fma(pk_fma(nsh2, ev2[p], w2tp[p]), am2, dfp);
    }

    pend = pend_new;
    if (act2 > 0.01f) last_seen = t;

    // prefetch step s+2 (stray tail reads stay inside ws)
    {
      const float* base = Kb + (size_t)(s + 2) * 512;
      kq0 = *(const f32x4*)(base + i * 16 + j0);
      kq1 = *(const f32x4*)(base + i * 16 + j0 + 4);
      vt = base[256 + i * 16 + k];
      gv = Gb[s + 2];
    }
  };

  for (int s = 0; s < S_DIM; s += 2) {
    step(s, kqA0, kqA1, vtA, gA);
    step(s + 1, kqB0, kqB1, vtB, gB);
  }
  LDS_BARRIER();
  if (tid == 0) {
    const f32x4* rp = (const f32x4*)&red[1][0];  // s=1023 parity = 1
    const f32x4 rs = rp[0] + rp[1];
    Eb[S_DIM - 1] = sqrtf((rs[0] + rs[1]) + (rs[2] + rs[3]));
  }
}

// ---------------------------------------------------------------------------
// GEMM2: out[8192][1024] = ysP[8192][256](bf16) @ WoP([1024][256])^T + bo
// ---------------------------------------------------------------------------
__global__ __launch_bounds__(256) void gemm_out(const unsigned short* __restrict__ ysbf,
                                                const float* __restrict__ WoP,
                                                const float* __restrict__ bo,
                                                float* __restrict__ out) {
  __shared__ unsigned short lsA[128 * 40];
  __shared__ unsigned short lsB[128 * 40];
  const int tid = threadIdx.x;
  const int row0 = blockIdx.y * 128;
  const int col0 = blockIdx.x * 128;
  const int sr = tid >> 1, sh = tid & 1;
  const unsigned short* ap = ysbf + (size_t)(row0 + sr) * 256 + sh * 16;
  const float* bp = WoP + (size_t)(col0 + sr) * 256 + sh * 16;
  unsigned short* wa = &lsA[sr * 40 + sh * 16];
  unsigned short* wb = &lsB[sr * 40 + sh * 16];

  const int lane = tid & 63;
  const int w = tid >> 6, wr = w >> 1, wc = w & 1;
  const int fr = lane & 15, fk = lane >> 4;

  f32x4 acc[4][4];
#pragma unroll
  for (int m = 0; m < 4; ++m)
#pragma unroll
    for (int n = 0; n < 4; ++n) acc[m][n] = (f32x4){0.f, 0.f, 0.f, 0.f};

  for (int kt = 0; kt < 8; ++kt) {
    u16x8 pa0 = *(const u16x8*)(ap + kt * 32);
    u16x8 pa1 = *(const u16x8*)(ap + kt * 32 + 8);
    const float* bq = bp + kt * 32;
    f32x4 B0 = *(const f32x4*)(bq + 0), B1 = *(const f32x4*)(bq + 4);
    f32x4 B2 = *(const f32x4*)(bq + 8), B3 = *(const f32x4*)(bq + 12);
    u16x8 pb0, pb1;
#pragma unroll
    for (int e = 0; e < 4; ++e) {
      pb0[e] = f2bf(B0[e]); pb0[e + 4] = f2bf(B1[e]);
      pb1[e] = f2bf(B2[e]); pb1[e + 4] = f2bf(B3[e]);
    }
    *(u16x8*)wa = pa0; *(u16x8*)(wa + 8) = pa1;
    *(u16x8*)wb = pb0; *(u16x8*)(wb + 8) = pb1;
    __syncthreads();
    bf16x8 af[4], bfr[4];
#pragma unroll
    for (int m = 0; m < 4; ++m)
      af[m] = *(const bf16x8*)(&lsA[(wr * 64 + m * 16 + fr) * 40 + fk * 8]);
#pragma unroll
    for (int n = 0; n < 4; ++n)
      bfr[n] = *(const bf16x8*)(&lsB[(wc * 64 + n * 16 + fr) * 40 + fk * 8]);
#pragma unroll
    for (int m = 0; m < 4; ++m)
#pragma unroll
      for (int n = 0; n < 4; ++n)
        acc[m][n] = __builtin_amdgcn_mfma_f32_16x16x32_bf16(af[m], bfr[n],
                                                            acc[m][n], 0, 0, 0);
    __syncthreads();
  }
#pragma unroll
  for (int m = 0; m < 4; ++m)
#pragma unroll
    for (int n = 0; n < 4; ++n) {
      const int col = col0 + wc * 64 + n * 16 + fr;
      const float bias = bo[col];
#pragma unroll
      for (int r = 0; r < 4; ++r) {
        const int row = row0 + wr * 64 + m * 16 + fk * 4 + r;
        out[(size_t)row * 1024 + col] = acc[m][n][r] + bias;
      }
    }
}

// ---------------------------------------------------------------------------
extern "C" void kernel_launch(void* const* d_in, const int* in_sizes, int n_in,
                              void* d_out, int out_size, void* d_ws, size_t ws_size,
                              hipStream_t stream) {
  const float* x = (const float*)d_in[0];
  const float* Wk = (const float*)d_in[1];
  const float* Wv = (const float*)d_in[2];
  const float* Wg = (const float*)d_in[3];
  const float* bg = (const float*)d_in[4];
  const float* Wo = (const float*)d_in[5];
  const float* bo = (const float*)d_in[6];

  float* out = (float*)d_out;                        // [8192][1024]
  float* err_out = out + (size_t)M_ROWS * 1024;      // [8192]

  char* ws = (char*)d_ws;
  float* KV = (float*)ws;                                        // 16 MB
  float* gate = (float*)(ws + (size_t)M_ROWS * 512 * 4);         // 32 KB
  unsigned short* ysbf =
      (unsigned short*)(ws + (size_t)M_ROWS * 512 * 4 + 32768);  // 4 MB
  float* WoP = (float*)(ws + (size_t)M_ROWS * 512 * 4 + 32768 +
                        (size_t)M_ROWS * 256 * 2);               // 1 MB

  gemm_kv<<<dim3(4, 64), 256, 0, stream>>>(x, Wk, Wv, KV);
  gate_kernel<<<dim3(2048), 256, 0, stream>>>(x, Wg, bg, gate);
  wo_perm<<<dim3(1024), 256, 0, stream>>>(Wo, WoP);
  scan_kernel<<<dim3(8), 512, 0, stream>>>(KV, gate, ysbf, err_out);
  gemm_out<<<dim3(8, 64), 256, 0, stream>>>(ysbf, WoP, bo, out);
}